// Round 1
// baseline (89.968 us; speedup 1.0000x reference)
//
#include <hip/hip_runtime.h>
#include <math.h>

// Problem constants (B,J,H,W fixed by the reference setup).
#define BB 256
#define JJ 17
#define HWN 4096            // H*W
#define WW 64
#define JP (JJ * HWN)       // 69632  (j,p) pairs per tensor
#define ROWS (BB * JJ)      // 4352   (b,j) rows per tensor

// -------- pass 1: per (tensor, j, p) compute m = max_b r, s = sum_b exp(r - m)
// s accumulated unshifted in double, rescaled once by exp(-m) in double:
// relative error ~1e-16 vs the true sum, well inside the reference's own
// f32 pairwise-summation error (~5e-7), so argmax decisions match.
__global__ __launch_bounds__(256) void pckh_pass1(
    const float* __restrict__ outp, const float* __restrict__ tgtp,
    float* __restrict__ M, float* __restrict__ S) {
  int gid = blockIdx.x * 256 + threadIdx.x;  // 0 .. 2*JP-1
  int t = gid / JP;
  int jp = gid - t * JP;
  const float* src = (t == 0 ? outp : tgtp) + jp;
  float m = -INFINITY;
  double s = 0.0;
#pragma unroll 8
  for (int b = 0; b < BB; ++b) {
    float v = src[(size_t)b * JP];
    m = fmaxf(m, v);
    s += (double)expf(v);
  }
  M[gid] = m;
  S[gid] = (float)(s * exp(-(double)m));
}

// -------- pass 2: per (tensor, b, j) row, argmax_p of expf(r-m)/s with
// first-occurrence tie-break (matches jnp.argmax).
__global__ __launch_bounds__(256) void pckh_pass2(
    const float* __restrict__ outp, const float* __restrict__ tgtp,
    const float* __restrict__ M, const float* __restrict__ S,
    int* __restrict__ IDX) {
  int blk = blockIdx.x;          // 0 .. 2*ROWS-1
  int t = blk / ROWS;
  int row = blk - t * ROWS;      // b*JJ + j
  int j = row % JJ;
  const float* src = (t ? tgtp : outp) + (size_t)row * HWN;
  const float* Mrow = M + (size_t)t * JP + (size_t)j * HWN;
  const float* Srow = S + (size_t)t * JP + (size_t)j * HWN;

  int tid = threadIdx.x;
  float bv = -1.0f;  // all sm values are > 0
  int bi = 0;
  for (int p = tid; p < HWN; p += 256) {
    float v = expf(src[p] - Mrow[p]) / Srow[p];   // IEEE f32 div, like XLA
    if (v > bv) { bv = v; bi = p; }               // strict > keeps earliest p
  }
  __shared__ float sv[256];
  __shared__ int si[256];
  sv[tid] = bv;
  si[tid] = bi;
  __syncthreads();
  for (int off = 128; off > 0; off >>= 1) {
    if (tid < off) {
      float v2 = sv[tid + off];
      int i2 = si[tid + off];
      if (v2 > sv[tid] || (v2 == sv[tid] && i2 < si[tid])) {
        sv[tid] = v2;
        si[tid] = i2;
      }
    }
    __syncthreads();
  }
  if (tid == 0) IDX[blk] = si[0];
}

// -------- pass 3: counts -> [avg, acc_j...]   (maxvals>0 mask is always true)
__global__ __launch_bounds__(256) void pckh_pass3(
    const int* __restrict__ IDX, float* __restrict__ outv) {
  __shared__ int num[JJ], below[JJ];
  __shared__ float accj[JJ];
  int tid = threadIdx.x;
  if (tid < JJ) { num[tid] = 0; below[tid] = 0; }
  __syncthreads();
  for (int row = tid; row < ROWS; row += 256) {
    int j = row % JJ;
    int io = IDX[row];          // output pred flat idx
    int it = IDX[ROWS + row];   // target pred flat idx
    float pox = (float)(io & (WW - 1));
    float poy = (float)(io >> 6);
    float ptx = (float)(it & (WW - 1));
    float pty = (float)(it >> 6);
    if (ptx > 1.0f && pty > 1.0f) {
      atomicAdd(&num[j], 1);
      const float nrm = 6.4f;  // float32(64)/float32(10), same as jnp
      float dx = (pox - ptx) / nrm;
      float dy = (poy - pty) / nrm;
      float d = sqrtf(dx * dx + dy * dy);
      if (d < 0.5f) atomicAdd(&below[j], 1);
    }
  }
  __syncthreads();
  if (tid < JJ) {
    accj[tid] = num[tid] > 0 ? (float)below[tid] / (float)num[tid] : -1.0f;
    outv[1 + tid] = accj[tid];
  }
  __syncthreads();
  if (tid == 0) {
    float sum = 0.0f;
    int cnt = 0;
    for (int j = 0; j < JJ; ++j)
      if (accj[j] >= 0.0f) { sum += accj[j]; cnt++; }
    outv[0] = cnt > 0 ? sum / (float)cnt : 0.0f;
  }
}

extern "C" void kernel_launch(void* const* d_in, const int* in_sizes, int n_in,
                              void* d_out, int out_size, void* d_ws, size_t ws_size,
                              hipStream_t stream) {
  const float* outp = (const float*)d_in[0];
  const float* tgtp = (const float*)d_in[1];
  // workspace layout: M[2*JP] f32 | S[2*JP] f32 | IDX[2*ROWS] i32  (~1.1 MB)
  float* M = (float*)d_ws;
  float* S = M + 2 * JP;
  int* IDX = (int*)(S + 2 * JP);
  float* outv = (float*)d_out;

  pckh_pass1<<<(2 * JP) / 256, 256, 0, stream>>>(outp, tgtp, M, S);
  pckh_pass2<<<2 * ROWS, 256, 0, stream>>>(outp, tgtp, M, S, IDX);
  pckh_pass3<<<1, 256, 0, stream>>>(IDX, outv);
}

// Round 2
// 81.013 us; speedup vs baseline: 1.1105x; 1.1105x over previous
//
#include <hip/hip_runtime.h>
#include <math.h>

// Problem constants (B,J,H,W fixed by the reference setup).
#define BB 256
#define JJ 17
#define HWN 4096            // H*W
#define WW 64
#define JP (JJ * HWN)       // 69632  (j,p) pairs per tensor
#define ROWS (BB * JJ)      // 4352   (b,j) rows per tensor

#define PBLK 128            // p-positions per block (float2 per lane)
#define BGRP 8              // batch groups (waves) per block

// -------- pass 1: per (tensor, j, p) compute m = max_b r, S = sum_b exp(r-m)
// Batch axis split across 8 waves (32 b each, float2 over p), LDS combine.
// Double accumulation (unshifted, rescaled by exp(-m) in double): ~1e-16
// relative error — far inside the reference's own f32 pairwise-sum error,
// so downstream argmax decisions match the reference bit-for-bit in f32.
__global__ __launch_bounds__(512) void pckh_pass1(
    const float* __restrict__ outp, const float* __restrict__ tgtp,
    float* __restrict__ M, float* __restrict__ S) {
  int blk = blockIdx.x;              // 0 .. 2*JP/PBLK - 1  (= 1087)
  int t = blk / (JP / PBLK);         // tensor select (JP/PBLK = 544)
  int pb = blk - t * (JP / PBLK);    // p-block within tensor
  const float* src = (t ? tgtp : outp) + (size_t)pb * PBLK;
  int tid = threadIdx.x;
  int lane = tid & 63;               // float2 index within the 128-p slab
  int bg = tid >> 6;                 // batch group 0..7

  float m0 = -INFINITY, m1 = -INFINITY;
  double s0 = 0.0, s1 = 0.0;
#pragma unroll 8
  for (int i = 0; i < BB / BGRP; ++i) {
    int b = bg * (BB / BGRP) + i;
    float2 v = *(const float2*)(src + (size_t)b * JP + lane * 2);
    m0 = fmaxf(m0, v.x);
    m1 = fmaxf(m1, v.y);
    s0 += (double)expf(v.x);
    s1 += (double)expf(v.y);
  }

  __shared__ float sm[BGRP][PBLK];
  __shared__ double ss[BGRP][PBLK];
  sm[bg][lane * 2] = m0;
  sm[bg][lane * 2 + 1] = m1;
  ss[bg][lane * 2] = s0;
  ss[bg][lane * 2 + 1] = s1;
  __syncthreads();

  if (tid < PBLK) {
    float m = sm[0][tid];
    double s = ss[0][tid];
#pragma unroll
    for (int g = 1; g < BGRP; ++g) {
      m = fmaxf(m, sm[g][tid]);
      s += ss[g][tid];
    }
    int gid = t * JP + pb * PBLK + tid;
    M[gid] = m;
    S[gid] = (float)(s * exp(-(double)m));
  }
}

// -------- pass 2: per (tensor, b, j) row, argmax_p of expf(r-m)/s with
// first-occurrence tie-break (matches jnp.argmax).
__global__ __launch_bounds__(256) void pckh_pass2(
    const float* __restrict__ outp, const float* __restrict__ tgtp,
    const float* __restrict__ M, const float* __restrict__ S,
    int* __restrict__ IDX) {
  int blk = blockIdx.x;          // 0 .. 2*ROWS-1
  int t = blk / ROWS;
  int row = blk - t * ROWS;      // b*JJ + j
  int j = row % JJ;
  const float* src = (t ? tgtp : outp) + (size_t)row * HWN;
  const float* Mrow = M + (size_t)t * JP + (size_t)j * HWN;
  const float* Srow = S + (size_t)t * JP + (size_t)j * HWN;

  int tid = threadIdx.x;
  float bv = -1.0f;  // all sm values are > 0
  int bi = 0;
  for (int p = tid; p < HWN; p += 256) {
    float v = expf(src[p] - Mrow[p]) / Srow[p];   // IEEE f32 div, like XLA
    if (v > bv) { bv = v; bi = p; }               // strict > keeps earliest p
  }
  __shared__ float sv[256];
  __shared__ int si[256];
  sv[tid] = bv;
  si[tid] = bi;
  __syncthreads();
  for (int off = 128; off > 0; off >>= 1) {
    if (tid < off) {
      float v2 = sv[tid + off];
      int i2 = si[tid + off];
      if (v2 > sv[tid] || (v2 == sv[tid] && i2 < si[tid])) {
        sv[tid] = v2;
        si[tid] = i2;
      }
    }
    __syncthreads();
  }
  if (tid == 0) IDX[blk] = si[0];
}

// -------- pass 3: counts -> [avg, acc_j...]   (maxvals>0 mask is always true)
__global__ __launch_bounds__(256) void pckh_pass3(
    const int* __restrict__ IDX, float* __restrict__ outv) {
  __shared__ int num[JJ], below[JJ];
  __shared__ float accj[JJ];
  int tid = threadIdx.x;
  if (tid < JJ) { num[tid] = 0; below[tid] = 0; }
  __syncthreads();
  for (int row = tid; row < ROWS; row += 256) {
    int j = row % JJ;
    int io = IDX[row];          // output pred flat idx
    int it = IDX[ROWS + row];   // target pred flat idx
    float pox = (float)(io & (WW - 1));
    float poy = (float)(io >> 6);
    float ptx = (float)(it & (WW - 1));
    float pty = (float)(it >> 6);
    if (ptx > 1.0f && pty > 1.0f) {
      atomicAdd(&num[j], 1);
      const float nrm = 6.4f;  // float32(64)/float32(10), same as jnp
      float dx = (pox - ptx) / nrm;
      float dy = (poy - pty) / nrm;
      float d = sqrtf(dx * dx + dy * dy);
      if (d < 0.5f) atomicAdd(&below[j], 1);
    }
  }
  __syncthreads();
  if (tid < JJ) {
    accj[tid] = num[tid] > 0 ? (float)below[tid] / (float)num[tid] : -1.0f;
    outv[1 + tid] = accj[tid];
  }
  __syncthreads();
  if (tid == 0) {
    float sum = 0.0f;
    int cnt = 0;
    for (int j = 0; j < JJ; ++j)
      if (accj[j] >= 0.0f) { sum += accj[j]; cnt++; }
    outv[0] = cnt > 0 ? sum / (float)cnt : 0.0f;
  }
}

extern "C" void kernel_launch(void* const* d_in, const int* in_sizes, int n_in,
                              void* d_out, int out_size, void* d_ws, size_t ws_size,
                              hipStream_t stream) {
  const float* outp = (const float*)d_in[0];
  const float* tgtp = (const float*)d_in[1];
  // workspace layout: M[2*JP] f32 | S[2*JP] f32 | IDX[2*ROWS] i32  (~1.1 MB)
  float* M = (float*)d_ws;
  float* S = M + 2 * JP;
  int* IDX = (int*)(S + 2 * JP);
  float* outv = (float*)d_out;

  pckh_pass1<<<(2 * JP) / PBLK, 512, 0, stream>>>(outp, tgtp, M, S);
  pckh_pass2<<<2 * ROWS, 256, 0, stream>>>(outp, tgtp, M, S, IDX);
  pckh_pass3<<<1, 256, 0, stream>>>(IDX, outv);
}

// Round 3
// 79.494 us; speedup vs baseline: 1.1318x; 1.0191x over previous
//
#include <hip/hip_runtime.h>
#include <math.h>

// Problem constants (B,J,H,W fixed by the reference setup).
#define BB 256
#define JJ 17
#define HWN 4096            // H*W
#define WW 64
#define JP (JJ * HWN)       // 69632  (j,p) pairs per tensor
#define ROWS (BB * JJ)      // 4352   (b,j) rows per tensor

// Tiled pass1: p-chunks of 2048 floats (8KB contiguous per block visit),
// batch split into 8 chunks of 32.
#define PC 2048
#define NPC (JP / PC)       // 34
#define NBC 8               // batch chunks
#define BPC (BB / NBC)      // 32

// -------- pass 1a: per (tensor, p-chunk, b-chunk) partial reduce.
// Each block reads 32 x 8KB contiguous bursts; reduction is in-thread
// (no LDS). Partials: float running max + UNSHIFTED double sum of exp,
// so cross-chunk combination in pass1b is exact to ~1e-16 relative.
__global__ __launch_bounds__(512) void pckh_pass1a(
    const float* __restrict__ outp, const float* __restrict__ tgtp,
    float* __restrict__ Pm, double* __restrict__ Ps) {
  int blk = blockIdx.x;               // 0 .. 2*NPC*NBC-1 (= 543)
  int t = blk / (NPC * NBC);
  int r = blk - t * (NPC * NBC);
  int pc = r / NBC;
  int bc = r - pc * NBC;
  int tid = threadIdx.x;
  const float* src = (t ? tgtp : outp) + (size_t)pc * PC + (size_t)tid * 4;
  float m0 = -INFINITY, m1 = -INFINITY, m2 = -INFINITY, m3 = -INFINITY;
  double s0 = 0.0, s1 = 0.0, s2 = 0.0, s3 = 0.0;
#pragma unroll 8
  for (int i = 0; i < BPC; ++i) {
    int b = bc * BPC + i;
    float4 v = *(const float4*)(src + (size_t)b * JP);
    m0 = fmaxf(m0, v.x); m1 = fmaxf(m1, v.y);
    m2 = fmaxf(m2, v.z); m3 = fmaxf(m3, v.w);
    s0 += (double)expf(v.x); s1 += (double)expf(v.y);
    s2 += (double)expf(v.z); s3 += (double)expf(v.w);
  }
  size_t pidx = ((size_t)(t * NBC + bc)) * JP + (size_t)pc * PC + (size_t)tid * 4;
  float4 mo = {m0, m1, m2, m3};
  *(float4*)(Pm + pidx) = mo;
  double2 sa = {s0, s1}, sb = {s2, s3};
  *(double2*)(Ps + pidx) = sa;
  *(double2*)(Ps + pidx + 2) = sb;
}

// -------- pass 1b: combine the 8 b-chunk partials -> M, S.
// S = (sum_b exp(r)) * exp(-m) in double, rounded once to f32 — identical
// values to the previous (verified absmax=0) formulation.
__global__ __launch_bounds__(256) void pckh_pass1b(
    const float* __restrict__ Pm, const double* __restrict__ Ps,
    float* __restrict__ M, float* __restrict__ S) {
  int gid = blockIdx.x * 256 + threadIdx.x;   // 0 .. 2*JP-1
  int t = gid / JP;
  int p = gid - t * JP;
  float m = -INFINITY;
  double s = 0.0;
#pragma unroll
  for (int bc = 0; bc < NBC; ++bc) {
    size_t idx = ((size_t)(t * NBC + bc)) * JP + p;
    m = fmaxf(m, Pm[idx]);
    s += Ps[idx];
  }
  M[gid] = m;
  S[gid] = (float)(s * exp(-(double)m));
}

// -------- fallback pass 1 (round-2 version) if d_ws can't hold partials.
#define PBLK 128
#define BGRP 8
__global__ __launch_bounds__(512) void pckh_pass1_fb(
    const float* __restrict__ outp, const float* __restrict__ tgtp,
    float* __restrict__ M, float* __restrict__ S) {
  int blk = blockIdx.x;
  int t = blk / (JP / PBLK);
  int pb = blk - t * (JP / PBLK);
  const float* src = (t ? tgtp : outp) + (size_t)pb * PBLK;
  int tid = threadIdx.x;
  int lane = tid & 63;
  int bg = tid >> 6;
  float m0 = -INFINITY, m1 = -INFINITY;
  double s0 = 0.0, s1 = 0.0;
#pragma unroll 8
  for (int i = 0; i < BB / BGRP; ++i) {
    int b = bg * (BB / BGRP) + i;
    float2 v = *(const float2*)(src + (size_t)b * JP + lane * 2);
    m0 = fmaxf(m0, v.x); m1 = fmaxf(m1, v.y);
    s0 += (double)expf(v.x); s1 += (double)expf(v.y);
  }
  __shared__ float sm[BGRP][PBLK];
  __shared__ double ss[BGRP][PBLK];
  sm[bg][lane * 2] = m0; sm[bg][lane * 2 + 1] = m1;
  ss[bg][lane * 2] = s0; ss[bg][lane * 2 + 1] = s1;
  __syncthreads();
  if (tid < PBLK) {
    float m = sm[0][tid];
    double s = ss[0][tid];
#pragma unroll
    for (int g = 1; g < BGRP; ++g) { m = fmaxf(m, sm[g][tid]); s += ss[g][tid]; }
    int gid = t * JP + pb * PBLK + tid;
    M[gid] = m;
    S[gid] = (float)(s * exp(-(double)m));
  }
}

// -------- pass 2: per (tensor, b, j) row, argmax_p of expf(r-m)/s with
// first-occurrence tie-break (matches jnp.argmax). float4 loads.
__global__ __launch_bounds__(256) void pckh_pass2(
    const float* __restrict__ outp, const float* __restrict__ tgtp,
    const float* __restrict__ M, const float* __restrict__ S,
    int* __restrict__ IDX) {
  int blk = blockIdx.x;          // 0 .. 2*ROWS-1
  int t = blk / ROWS;
  int row = blk - t * ROWS;      // b*JJ + j
  int j = row % JJ;
  const float4* src4 = (const float4*)((t ? tgtp : outp) + (size_t)row * HWN);
  const float4* M4 = (const float4*)(M + (size_t)t * JP + (size_t)j * HWN);
  const float4* S4 = (const float4*)(S + (size_t)t * JP + (size_t)j * HWN);

  int tid = threadIdx.x;
  float bv = -1.0f;  // all sm values are > 0
  int bi = 0;
#pragma unroll
  for (int g = 0; g < 4; ++g) {
    int p4 = g * 256 + tid;      // ascending p within thread
    float4 v = src4[p4];
    float4 m4 = M4[p4];
    float4 s4 = S4[p4];
    int p = p4 * 4;
    float e;
    e = expf(v.x - m4.x) / s4.x; if (e > bv) { bv = e; bi = p; }
    e = expf(v.y - m4.y) / s4.y; if (e > bv) { bv = e; bi = p + 1; }
    e = expf(v.z - m4.z) / s4.z; if (e > bv) { bv = e; bi = p + 2; }
    e = expf(v.w - m4.w) / s4.w; if (e > bv) { bv = e; bi = p + 3; }
  }
  __shared__ float sv[256];
  __shared__ int si[256];
  sv[tid] = bv;
  si[tid] = bi;
  __syncthreads();
  for (int off = 128; off > 0; off >>= 1) {
    if (tid < off) {
      float v2 = sv[tid + off];
      int i2 = si[tid + off];
      if (v2 > sv[tid] || (v2 == sv[tid] && i2 < si[tid])) {
        sv[tid] = v2;
        si[tid] = i2;
      }
    }
    __syncthreads();
  }
  if (tid == 0) IDX[blk] = si[0];
}

// -------- pass 3: counts -> [avg, acc_j...]   (maxvals>0 mask is always true)
__global__ __launch_bounds__(256) void pckh_pass3(
    const int* __restrict__ IDX, float* __restrict__ outv) {
  __shared__ int num[JJ], below[JJ];
  __shared__ float accj[JJ];
  int tid = threadIdx.x;
  if (tid < JJ) { num[tid] = 0; below[tid] = 0; }
  __syncthreads();
  for (int row = tid; row < ROWS; row += 256) {
    int j = row % JJ;
    int io = IDX[row];
    int it = IDX[ROWS + row];
    float pox = (float)(io & (WW - 1));
    float poy = (float)(io >> 6);
    float ptx = (float)(it & (WW - 1));
    float pty = (float)(it >> 6);
    if (ptx > 1.0f && pty > 1.0f) {
      atomicAdd(&num[j], 1);
      const float nrm = 6.4f;  // float32(64)/float32(10), same as jnp
      float dx = (pox - ptx) / nrm;
      float dy = (poy - pty) / nrm;
      float d = sqrtf(dx * dx + dy * dy);
      if (d < 0.5f) atomicAdd(&below[j], 1);
    }
  }
  __syncthreads();
  if (tid < JJ) {
    accj[tid] = num[tid] > 0 ? (float)below[tid] / (float)num[tid] : -1.0f;
    outv[1 + tid] = accj[tid];
  }
  __syncthreads();
  if (tid == 0) {
    float sum = 0.0f;
    int cnt = 0;
    for (int j = 0; j < JJ; ++j)
      if (accj[j] >= 0.0f) { sum += accj[j]; cnt++; }
    outv[0] = cnt > 0 ? sum / (float)cnt : 0.0f;
  }
}

extern "C" void kernel_launch(void* const* d_in, const int* in_sizes, int n_in,
                              void* d_out, int out_size, void* d_ws, size_t ws_size,
                              hipStream_t stream) {
  const float* outp = (const float*)d_in[0];
  const float* tgtp = (const float*)d_in[1];
  float* outv = (float*)d_out;

  // workspace layout: M[2*JP] f32 | S[2*JP] f32 | IDX[2*ROWS] i32 |
  //                   Pm[2*NBC*JP] f32 | Ps[2*NBC*JP] f64
  float* M = (float*)d_ws;
  float* S = M + 2 * JP;
  int* IDX = (int*)(S + 2 * JP);
  size_t base = (size_t)2 * JP * 4 * 2 + (size_t)2 * ROWS * 4;  // bytes used so far
  base = (base + 255) & ~(size_t)255;                            // align 256
  size_t pm_bytes = (size_t)2 * NBC * JP * sizeof(float);        // 4,456,448 (256-mult)
  size_t ps_bytes = (size_t)2 * NBC * JP * sizeof(double);
  float* Pm = (float*)((char*)d_ws + base);
  double* Ps = (double*)((char*)d_ws + base + pm_bytes);
  size_t need = base + pm_bytes + ps_bytes;

  if (ws_size >= need) {
    pckh_pass1a<<<2 * NPC * NBC, 512, 0, stream>>>(outp, tgtp, Pm, Ps);
    pckh_pass1b<<<(2 * JP) / 256, 256, 0, stream>>>(Pm, Ps, M, S);
  } else {
    pckh_pass1_fb<<<(2 * JP) / PBLK, 512, 0, stream>>>(outp, tgtp, M, S);
  }
  pckh_pass2<<<2 * ROWS, 256, 0, stream>>>(outp, tgtp, M, S, IDX);
  pckh_pass3<<<1, 256, 0, stream>>>(IDX, outv);
}

// Round 4
// 75.622 us; speedup vs baseline: 1.1897x; 1.0512x over previous
//
#include <hip/hip_runtime.h>
#include <math.h>

// Problem constants (B,J,H,W fixed by the reference setup).
#define BB 256
#define JJ 17
#define HWN 4096            // H*W
#define WW 64
#define JP (JJ * HWN)       // 69632  (j,p) pairs per tensor
#define ROWS (BB * JJ)      // 4352   (b,j) rows per tensor

// Tiled pass1: p-chunks of 1024 floats (4KB contiguous per row-visit),
// batch split into 8 chunks of 32. 256-thread blocks -> 1088 blocks total
// (4.25 blocks/CU: small tail, many waves in flight).
#define PC 1024
#define NPC (JP / PC)       // 68
#define NBC 8               // batch chunks
#define BPC (BB / NBC)      // 32

// -------- pass 1a: per (tensor, p-chunk, b-chunk) partial reduce.
// In-thread reduction (no LDS). Partials: float running max + UNSHIFTED
// double sum of exp, so cross-chunk combination in pass1b is exact to
// ~1e-16 relative (same numerics as the absmax=0-verified version).
__global__ __launch_bounds__(256) void pckh_pass1a(
    const float* __restrict__ outp, const float* __restrict__ tgtp,
    float* __restrict__ Pm, double* __restrict__ Ps) {
  int blk = blockIdx.x;               // 0 .. 2*NPC*NBC-1 (= 1087)
  int t = blk / (NPC * NBC);
  int r = blk - t * (NPC * NBC);
  int pc = r / NBC;
  int bc = r - pc * NBC;
  int tid = threadIdx.x;
  const float* src = (t ? tgtp : outp) + (size_t)pc * PC + (size_t)tid * 4;
  float m0 = -INFINITY, m1 = -INFINITY, m2 = -INFINITY, m3 = -INFINITY;
  double s0 = 0.0, s1 = 0.0, s2 = 0.0, s3 = 0.0;
#pragma unroll 16
  for (int i = 0; i < BPC; ++i) {
    int b = bc * BPC + i;
    float4 v = *(const float4*)(src + (size_t)b * JP);
    m0 = fmaxf(m0, v.x); m1 = fmaxf(m1, v.y);
    m2 = fmaxf(m2, v.z); m3 = fmaxf(m3, v.w);
    s0 += (double)expf(v.x); s1 += (double)expf(v.y);
    s2 += (double)expf(v.z); s3 += (double)expf(v.w);
  }
  size_t pidx = ((size_t)(t * NBC + bc)) * JP + (size_t)pc * PC + (size_t)tid * 4;
  float4 mo = {m0, m1, m2, m3};
  *(float4*)(Pm + pidx) = mo;
  double2 sa = {s0, s1}, sb = {s2, s3};
  *(double2*)(Ps + pidx) = sa;
  *(double2*)(Ps + pidx + 2) = sb;
}

// -------- pass 1b: combine the 8 b-chunk partials -> M, S.
// S = (sum_b exp(r)) * exp(-m) in double, rounded once to f32 — identical
// values to the absmax=0-verified formulation.
__global__ __launch_bounds__(256) void pckh_pass1b(
    const float* __restrict__ Pm, const double* __restrict__ Ps,
    float* __restrict__ M, float* __restrict__ S) {
  int gid = blockIdx.x * 256 + threadIdx.x;   // 0 .. 2*JP-1
  int t = gid / JP;
  int p = gid - t * JP;
  float m = -INFINITY;
  double s = 0.0;
#pragma unroll
  for (int bc = 0; bc < NBC; ++bc) {
    size_t idx = ((size_t)(t * NBC + bc)) * JP + p;
    m = fmaxf(m, Pm[idx]);
    s += Ps[idx];
  }
  M[gid] = m;
  S[gid] = (float)(s * exp(-(double)m));
}

// -------- fallback pass 1 (round-2 version) if d_ws can't hold partials.
#define PBLK 128
#define BGRP 8
__global__ __launch_bounds__(512) void pckh_pass1_fb(
    const float* __restrict__ outp, const float* __restrict__ tgtp,
    float* __restrict__ M, float* __restrict__ S) {
  int blk = blockIdx.x;
  int t = blk / (JP / PBLK);
  int pb = blk - t * (JP / PBLK);
  const float* src = (t ? tgtp : outp) + (size_t)pb * PBLK;
  int tid = threadIdx.x;
  int lane = tid & 63;
  int bg = tid >> 6;
  float m0 = -INFINITY, m1 = -INFINITY;
  double s0 = 0.0, s1 = 0.0;
#pragma unroll 8
  for (int i = 0; i < BB / BGRP; ++i) {
    int b = bg * (BB / BGRP) + i;
    float2 v = *(const float2*)(src + (size_t)b * JP + lane * 2);
    m0 = fmaxf(m0, v.x); m1 = fmaxf(m1, v.y);
    s0 += (double)expf(v.x); s1 += (double)expf(v.y);
  }
  __shared__ float sm[BGRP][PBLK];
  __shared__ double ss[BGRP][PBLK];
  sm[bg][lane * 2] = m0; sm[bg][lane * 2 + 1] = m1;
  ss[bg][lane * 2] = s0; ss[bg][lane * 2 + 1] = s1;
  __syncthreads();
  if (tid < PBLK) {
    float m = sm[0][tid];
    double s = ss[0][tid];
#pragma unroll
    for (int g = 1; g < BGRP; ++g) { m = fmaxf(m, sm[g][tid]); s += ss[g][tid]; }
    int gid = t * JP + pb * PBLK + tid;
    M[gid] = m;
    S[gid] = (float)(s * exp(-(double)m));
  }
}

// -------- pass 2: per (tensor, b, j) row, argmax_p of expf(r-m)/s with
// first-occurrence tie-break (matches jnp.argmax). float4 loads.
__global__ __launch_bounds__(256) void pckh_pass2(
    const float* __restrict__ outp, const float* __restrict__ tgtp,
    const float* __restrict__ M, const float* __restrict__ S,
    int* __restrict__ IDX) {
  int blk = blockIdx.x;          // 0 .. 2*ROWS-1
  int t = blk / ROWS;
  int row = blk - t * ROWS;      // b*JJ + j
  int j = row % JJ;
  const float4* src4 = (const float4*)((t ? tgtp : outp) + (size_t)row * HWN);
  const float4* M4 = (const float4*)(M + (size_t)t * JP + (size_t)j * HWN);
  const float4* S4 = (const float4*)(S + (size_t)t * JP + (size_t)j * HWN);

  int tid = threadIdx.x;
  float bv = -1.0f;  // all sm values are > 0
  int bi = 0;
#pragma unroll
  for (int g = 0; g < 4; ++g) {
    int p4 = g * 256 + tid;      // ascending p within thread
    float4 v = src4[p4];
    float4 m4 = M4[p4];
    float4 s4 = S4[p4];
    int p = p4 * 4;
    float e;
    e = expf(v.x - m4.x) / s4.x; if (e > bv) { bv = e; bi = p; }
    e = expf(v.y - m4.y) / s4.y; if (e > bv) { bv = e; bi = p + 1; }
    e = expf(v.z - m4.z) / s4.z; if (e > bv) { bv = e; bi = p + 2; }
    e = expf(v.w - m4.w) / s4.w; if (e > bv) { bv = e; bi = p + 3; }
  }
  __shared__ float sv[256];
  __shared__ int si[256];
  sv[tid] = bv;
  si[tid] = bi;
  __syncthreads();
  for (int off = 128; off > 0; off >>= 1) {
    if (tid < off) {
      float v2 = sv[tid + off];
      int i2 = si[tid + off];
      if (v2 > sv[tid] || (v2 == sv[tid] && i2 < si[tid])) {
        sv[tid] = v2;
        si[tid] = i2;
      }
    }
    __syncthreads();
  }
  if (tid == 0) IDX[blk] = si[0];
}

// -------- pass 3: counts -> [avg, acc_j...]   (maxvals>0 mask is always true)
__global__ __launch_bounds__(256) void pckh_pass3(
    const int* __restrict__ IDX, float* __restrict__ outv) {
  __shared__ int num[JJ], below[JJ];
  __shared__ float accj[JJ];
  int tid = threadIdx.x;
  if (tid < JJ) { num[tid] = 0; below[tid] = 0; }
  __syncthreads();
  for (int row = tid; row < ROWS; row += 256) {
    int j = row % JJ;
    int io = IDX[row];
    int it = IDX[ROWS + row];
    float pox = (float)(io & (WW - 1));
    float poy = (float)(io >> 6);
    float ptx = (float)(it & (WW - 1));
    float pty = (float)(it >> 6);
    if (ptx > 1.0f && pty > 1.0f) {
      atomicAdd(&num[j], 1);
      const float nrm = 6.4f;  // float32(64)/float32(10), same as jnp
      float dx = (pox - ptx) / nrm;
      float dy = (poy - pty) / nrm;
      float d = sqrtf(dx * dx + dy * dy);
      if (d < 0.5f) atomicAdd(&below[j], 1);
    }
  }
  __syncthreads();
  if (tid < JJ) {
    accj[tid] = num[tid] > 0 ? (float)below[tid] / (float)num[tid] : -1.0f;
    outv[1 + tid] = accj[tid];
  }
  __syncthreads();
  if (tid == 0) {
    float sum = 0.0f;
    int cnt = 0;
    for (int j = 0; j < JJ; ++j)
      if (accj[j] >= 0.0f) { sum += accj[j]; cnt++; }
    outv[0] = cnt > 0 ? sum / (float)cnt : 0.0f;
  }
}

extern "C" void kernel_launch(void* const* d_in, const int* in_sizes, int n_in,
                              void* d_out, int out_size, void* d_ws, size_t ws_size,
                              hipStream_t stream) {
  const float* outp = (const float*)d_in[0];
  const float* tgtp = (const float*)d_in[1];
  float* outv = (float*)d_out;

  // workspace layout: M[2*JP] f32 | S[2*JP] f32 | IDX[2*ROWS] i32 |
  //                   Pm[2*NBC*JP] f32 | Ps[2*NBC*JP] f64
  float* M = (float*)d_ws;
  float* S = M + 2 * JP;
  int* IDX = (int*)(S + 2 * JP);
  size_t base = (size_t)2 * JP * 4 * 2 + (size_t)2 * ROWS * 4;  // bytes used so far
  base = (base + 255) & ~(size_t)255;                            // align 256
  size_t pm_bytes = (size_t)2 * NBC * JP * sizeof(float);
  size_t ps_bytes = (size_t)2 * NBC * JP * sizeof(double);
  float* Pm = (float*)((char*)d_ws + base);
  double* Ps = (double*)((char*)d_ws + base + pm_bytes);
  size_t need = base + pm_bytes + ps_bytes;

  if (ws_size >= need) {
    pckh_pass1a<<<2 * NPC * NBC, 256, 0, stream>>>(outp, tgtp, Pm, Ps);
    pckh_pass1b<<<(2 * JP) / 256, 256, 0, stream>>>(Pm, Ps, M, S);
  } else {
    pckh_pass1_fb<<<(2 * JP) / PBLK, 512, 0, stream>>>(outp, tgtp, M, S);
  }
  pckh_pass2<<<2 * ROWS, 256, 0, stream>>>(outp, tgtp, M, S, IDX);
  pckh_pass3<<<1, 256, 0, stream>>>(IDX, outv);
}